// Round 1
// baseline (1572.459 us; speedup 1.0000x reference)
//
#include <hip/hip_runtime.h>

// DiffusionBlock: 20 steps of depthwise 3x3 stencil with reflect padding
// on x: (16, 2, 1024, 1024) fp32. weight: (2,1,3,3) fp32, time_steps: int (=20).
//
// Each step: out[i][j] = sum_{di,dj} w[c][di][dj] * h[refl(i+di-1)][refl(j+dj-1)]
// with reflect: index -1 -> 1, index N -> N-2.

#define IMG_H 1024
#define IMG_W 1024
#define NPLANES 32   // 16 batch * 2 channels
#define TSTEPS 20

__global__ __launch_bounds__(256) void diff_step(
    const float* __restrict__ src, float* __restrict__ dst,
    const float* __restrict__ wt)
{
    const int row   = blockIdx.x;        // 0..1023
    const int plane = blockIdx.y;        // 0..31, n*2 + c
    const int c     = plane & 1;
    const size_t base = (size_t)plane * IMG_H * IMG_W;
    const float* sp = src + base;
    float*       dp = dst + base;

    __shared__ __align__(16) float lds[3][IMG_W];

    const int t = threadIdx.x;           // 0..255, handles cols 4t..4t+3

    // reflect row indices
    const int rm1 = (row == 0)         ? 1         : row - 1;
    const int rp1 = (row == IMG_H - 1) ? IMG_H - 2 : row + 1;

    // coalesced float4 stage of the 3 source rows into LDS
    ((float4*)lds[0])[t] = ((const float4*)(sp + (size_t)rm1 * IMG_W))[t];
    ((float4*)lds[1])[t] = ((const float4*)(sp + (size_t)row * IMG_W))[t];
    ((float4*)lds[2])[t] = ((const float4*)(sp + (size_t)rp1 * IMG_W))[t];

    // per-channel 3x3 weights (broadcast scalar loads; L1/L2 resident)
    const float* w9 = wt + c * 9;
    const float w00 = w9[0], w01 = w9[1], w02 = w9[2];
    const float w10 = w9[3], w11 = w9[4], w12 = w9[5];
    const float w20 = w9[6], w21 = w9[7], w22 = w9[8];

    __syncthreads();

    // column-reflect for this thread's 4-wide slab:
    // left neighbor of col 0 is col 1; right neighbor of col 1023 is col 1022
    const int li = (t == 0)   ? 1         : 4 * t - 1;
    const int ri = (t == 255) ? IMG_W - 2 : 4 * t + 4;

    float acc0 = 0.f, acc1 = 0.f, acc2 = 0.f, acc3 = 0.f;

    #pragma unroll
    for (int r = 0; r < 3; ++r) {
        const float wl = (r == 0) ? w00 : (r == 1) ? w10 : w20;
        const float wc = (r == 0) ? w01 : (r == 1) ? w11 : w21;
        const float wr = (r == 0) ? w02 : (r == 1) ? w12 : w22;
        const float4 m = ((const float4*)lds[r])[t];  // cols 4t..4t+3
        const float lv = lds[r][li];                  // col 4t-1 (reflected)
        const float rv = lds[r][ri];                  // col 4t+4 (reflected)
        // v[-1..4] = {lv, m.x, m.y, m.z, m.w, rv}
        acc0 += wl * lv  + wc * m.x + wr * m.y;
        acc1 += wl * m.x + wc * m.y + wr * m.z;
        acc2 += wl * m.y + wc * m.z + wr * m.w;
        acc3 += wl * m.z + wc * m.w + wr * rv;
    }

    float4 out;
    out.x = acc0; out.y = acc1; out.z = acc2; out.w = acc3;
    ((float4*)dp)[(size_t)row * (IMG_W / 4) + t] = out;
}

extern "C" void kernel_launch(void* const* d_in, const int* in_sizes, int n_in,
                              void* d_out, int out_size, void* d_ws, size_t ws_size,
                              hipStream_t stream) {
    const float* x  = (const float*)d_in[0];
    const float* wt = (const float*)d_in[1];
    float* out = (float*)d_out;
    float* ws  = (float*)d_ws;   // needs >= 128 MiB (one tensor copy)

    dim3 grid(IMG_H, NPLANES);
    dim3 block(256);

    // Ping-pong: x -> ws -> out -> ws -> ... ; step 19 (odd) writes d_out.
    const float* src = x;
    for (int s = 0; s < TSTEPS; ++s) {
        float* dst = ((s & 1) == 0) ? ws : out;
        diff_step<<<grid, block, 0, stream>>>(src, dst, wt);
        src = dst;
    }
}

// Round 2
// 692.026 us; speedup vs baseline: 2.2723x; 2.2723x over previous
//
#include <hip/hip_runtime.h>

// DiffusionBlock: 20 steps of depthwise 3x3 stencil with reflect padding on
// (16,2,1024,1024) fp32. Fused: 5 steps per launch, 4 launches.
//
// Per block: one 64x64 output tile. LDS buffer 74 rows x 84 cols (row halo 5,
// col halo 8 left / up to 12 right for alignment), loaded with reflected
// indices. The stencil weights are symmetric (w_l==w_r, w_t==w_b per
// make_stencil_weight), so mirror-extension at load + plain stencil == reflect
// BC at every step. Double-buffered LDS, 5 steps, store interior.
//
// Validity: buffer ring r (distance to buffer edge) holds exact step-s values
// for s <= r. Computed window = rows 1..72, cols 0..79 (20 float4 strips).
// Output needs rows 5..68 (ring>=5, K=5 exact) and cols 8..71 (ring>=8 > 5).

#define IMG 1024
#define NPL 32
#define TILE 64
#define CH 8          // col halo (left); loaded cols: c0-8 .. c0+75
#define RH 5          // row halo
#define K 5           // fused steps per launch
#define BROWS 74      // TILE + 2*RH
#define ST 84         // LDS row stride in floats (84*4B = 336B, 16B aligned)
#define BSZ (BROWS*ST)

__device__ __forceinline__ int refl(int i) {
    i = (i < 0) ? -i : i;
    return (i >= IMG) ? (2*(IMG-1) - i) : i;
}

__global__ __launch_bounds__(256) void diff5(
    const float* __restrict__ src, float* __restrict__ dst,
    const float* __restrict__ wt)
{
    const int tid = threadIdx.x;
    const int tx = blockIdx.x & 15, ty = blockIdx.x >> 4;
    const int plane = blockIdx.y;
    const int r0 = ty * TILE, c0 = tx * TILE;
    const float* sp = src + (size_t)plane * IMG * IMG;
    float*       dp = dst + (size_t)plane * IMG * IMG;

    __shared__ __align__(16) float S[2 * BSZ];
    float* A = S;
    float* B = S + BSZ;

    const float* w9 = wt + (plane & 1) * 9;
    const float w00=w9[0], w01=w9[1], w02=w9[2];
    const float w10=w9[3], w11=w9[4], w12=w9[5];
    const float w20=w9[6], w21=w9[7], w22=w9[8];

    // ---- load extended tile into A ----
    if (tx >= 1 && tx <= 14 && ty >= 1 && ty <= 14) {
        // interior: vectorized, 21 float4 per row (84 cols), no reflect needed
        const float* base = sp + (size_t)(r0 - RH) * IMG + (c0 - CH);
        for (int i = tid; i < BROWS * 21; i += 256) {
            const int r = i / 21, q = i % 21;
            *(float4*)(A + r * ST + 4 * q) =
                *(const float4*)(base + (size_t)r * IMG + 4 * q);
        }
    } else {
        // edge tile: scalar loads with reflected indices
        for (int i = tid; i < BSZ; i += 256) {
            const int r = i / ST, cc = i % ST;
            A[i] = sp[(size_t)refl(r0 - RH + r) * IMG + refl(c0 - CH + cc)];
        }
    }
    __syncthreads();

    // ---- 5 fused stencil steps in LDS ----
    // 240 active threads: strip j = tid%20 (cols 4j..4j+3), chunk q = tid/20
    // (6 output rows each, rows 1..72).
    const int j    = tid % 20;
    const int qc   = tid / 20;
    const bool act = (tid < 240);
    const int rs   = 1 + 6 * qc;
    const int lane = tid & 63;
    // lanes whose shfl neighbor is in another wave need a real LDS read;
    // strip edges j==0 / j==19 feed invalid rings, garbage allowed.
    const bool lbad = (lane == 0)  && (j != 0);
    const bool rbad = (lane == 63) && (j != 19);

    float* cur = A; float* nxt = B;
    for (int s = 0; s < K; ++s) {
        if (act) {
            const float* rp = cur + (rs - 1) * ST + 4 * j;
            float4 m0 = *(const float4*)rp;
            float  l0 = __shfl_up(m0.w, 1), r0v = __shfl_down(m0.x, 1);
            if (lbad) l0  = rp[-1];
            if (rbad) r0v = rp[4];
            const float* rp1 = rp + ST;
            float4 m1 = *(const float4*)rp1;
            float  l1 = __shfl_up(m1.w, 1), r1v = __shfl_down(m1.x, 1);
            if (lbad) l1  = rp1[-1];
            if (rbad) r1v = rp1[4];

            float* op = nxt + rs * ST + 4 * j;
            #pragma unroll
            for (int i2 = 0; i2 < 6; ++i2) {
                const float* rp2 = rp + (i2 + 2) * ST;
                float4 m2 = *(const float4*)rp2;
                float  l2 = __shfl_up(m2.w, 1), r2v = __shfl_down(m2.x, 1);
                if (lbad) l2  = rp2[-1];
                if (rbad) r2v = rp2[4];

                float4 o;
                o.x = w00*l0   + w01*m0.x + w02*m0.y
                    + w10*l1   + w11*m1.x + w12*m1.y
                    + w20*l2   + w21*m2.x + w22*m2.y;
                o.y = w00*m0.x + w01*m0.y + w02*m0.z
                    + w10*m1.x + w11*m1.y + w12*m1.z
                    + w20*m2.x + w21*m2.y + w22*m2.z;
                o.z = w00*m0.y + w01*m0.z + w02*m0.w
                    + w10*m1.y + w11*m1.z + w12*m1.w
                    + w20*m2.y + w21*m2.z + w22*m2.w;
                o.w = w00*m0.z + w01*m0.w + w02*r0v
                    + w10*m1.z + w11*m1.w + w12*r1v
                    + w20*m2.z + w21*m2.w + w22*r2v;
                *(float4*)(op + i2 * ST) = o;

                l0 = l1; m0 = m1; r0v = r1v;
                l1 = l2; m1 = m2; r1v = r2v;
            }
        }
        __syncthreads();
        float* t = cur; cur = nxt; nxt = t;
    }

    // ---- store valid 64x64 interior (rows 5..68, cols 8..71) ----
    for (int i = tid; i < TILE * 16; i += 256) {
        const int rr = i >> 4, cc = i & 15;
        *(float4*)(dp + (size_t)(r0 + rr) * IMG + c0 + 4 * cc) =
            *(const float4*)(cur + (RH + rr) * ST + CH + 4 * cc);
    }
}

extern "C" void kernel_launch(void* const* d_in, const int* in_sizes, int n_in,
                              void* d_out, int out_size, void* d_ws, size_t ws_size,
                              hipStream_t stream) {
    const float* x  = (const float*)d_in[0];
    const float* wt = (const float*)d_in[1];
    float* out = (float*)d_out;
    float* ws  = (float*)d_ws;    // needs >= 128 MiB (one tensor copy)

    dim3 g(256, NPL), b(256);
    // 20 steps = 4 launches x 5 fused steps; ping-pong ends in d_out.
    diff5<<<g, b, 0, stream>>>(x,   ws,  wt);
    diff5<<<g, b, 0, stream>>>(ws,  out, wt);
    diff5<<<g, b, 0, stream>>>(out, ws,  wt);
    diff5<<<g, b, 0, stream>>>(ws,  out, wt);
}